// Round 3
// baseline (465.334 us; speedup 1.0000x reference)
//
#include <hip/hip_runtime.h>

#define EMBED 1024
#define SEQ 2048
#define BATCH 8

typedef __bf16 bf16;
typedef bf16 bf16x4 __attribute__((ext_vector_type(4)));
typedef bf16 bf16x8 __attribute__((ext_vector_type(8)));
typedef float f32x4 __attribute__((ext_vector_type(4)));

__device__ __forceinline__ void async_copy16(const bf16* g, bf16* l) {
  __builtin_amdgcn_global_load_lds(
      (const __attribute__((address_space(1))) unsigned int*)g,
      (__attribute__((address_space(3))) unsigned int*)l, 16, 0, 0);
}

// ========== chained 256x256 BK=64 GEMM core (T2+T3+T4+T5) ==========
// Runs NSUB sub-GEMMs (A fixed 256 rows, B advances by bstride per sub) as ONE
// continuous software pipeline: double-buffered LDS, 2-tile-deep prefetch with
// counted vmcnt(8) that never drains inside the chain; epi(sub, acc) fires at
// each sub boundary while next-sub loads are already in flight.
// 512 threads = 8 waves (2M x 4N); per-wave 128x64 out = acc[8][4] f32x4.
// LDS: 2 x (A 256x64 + B 256x64) bf16 = 128 KiB, XOR-swizzled 16B slots.
template <int NSUB, int KT, int LDA, int LDB, class EpiF>
__device__ __forceinline__ void gemm_chain(const bf16* __restrict__ Ab,
                                           const bf16* __restrict__ Bb,
                                           size_t bstride, bf16* lds, EpiF&& epi) {
  constexpr int TOT = NSUB * KT;
  const int tid = (int)threadIdx.x;
  const int lane = tid & 63;
  const int wid = tid >> 6;
  const int wm = wid >> 2, wn = wid & 3;
  const int c = lane & 15, g = lane >> 4;
  const int sx = c & 7;

  // linear LDS dest + inverse-swizzled global source (both-sides rule)
  int srow[4], scol[4];
#pragma unroll
  for (int r = 0; r < 4; ++r) {
    int idx = r * 512 + tid;
    srow[r] = idx >> 3;
    scol[r] = ((idx & 7) ^ ((idx >> 3) & 7)) * 8;
  }

  f32x4 acc[8][4];
#pragma unroll
  for (int i = 0; i < 8; ++i)
#pragma unroll
    for (int j = 0; j < 4; ++j) acc[i][j] = (f32x4){0.f, 0.f, 0.f, 0.f};

  auto stage = [&](int t) {
    bf16* dst = lds + (t & 1) * 32768;
    const int sub = t / KT;
    const int k0 = (t % KT) * 64;
    const bf16* As = Ab + k0;
    const bf16* Bs = Bb + (size_t)sub * bstride + k0;
#pragma unroll
    for (int r = 0; r < 4; ++r)
      async_copy16(As + (size_t)srow[r] * LDA + scol[r], dst + (r * 512 + tid) * 8);
#pragma unroll
    for (int r = 0; r < 4; ++r)
      async_copy16(Bs + (size_t)srow[r] * LDB + scol[r], dst + 16384 + (r * 512 + tid) * 8);
  };

  stage(0);
  stage(1);
  asm volatile("s_waitcnt vmcnt(8)" ::: "memory");  // tile 0 landed (mine)
  __builtin_amdgcn_s_barrier();                     // tile 0 landed (everyone)

  const int aoffb = (wm * 128 + c) * 64;
  const int boffb = (wn * 64 + c) * 64;

  for (int t = 0; t < TOT; ++t) {
    const bf16* bufA = lds + (t & 1) * 32768;
    const bf16* bufB = bufA + 16384;
    bf16x8 bfr[4][2];
#pragma unroll
    for (int p = 0; p < 4; ++p) {
      bf16x8 afr[2][2];
#pragma unroll
      for (int mm = 0; mm < 2; ++mm)
#pragma unroll
        for (int ks = 0; ks < 2; ++ks)
          afr[mm][ks] = *reinterpret_cast<const bf16x8*>(
              bufA + aoffb + (p * 2 + mm) * 1024 + (((ks * 4 + g) ^ sx) * 8));
      if (p == 0) {
#pragma unroll
        for (int ni = 0; ni < 4; ++ni)
#pragma unroll
          for (int ks = 0; ks < 2; ++ks)
            bfr[ni][ks] = *reinterpret_cast<const bf16x8*>(
                bufB + boffb + ni * 1024 + (((ks * 4 + g) ^ sx) * 8));
      }
      __builtin_amdgcn_s_barrier();
      asm volatile("s_waitcnt lgkmcnt(0)" ::: "memory");
      __builtin_amdgcn_sched_barrier(0);
      __builtin_amdgcn_s_setprio(1);
#pragma unroll
      for (int mm = 0; mm < 2; ++mm)
#pragma unroll
        for (int ni = 0; ni < 4; ++ni)
#pragma unroll
          for (int ks = 0; ks < 2; ++ks)
            acc[p * 2 + mm][ni] = __builtin_amdgcn_mfma_f32_16x16x32_bf16(
                afr[mm][ks], bfr[ni][ks], acc[p * 2 + mm][ni], 0, 0, 0);
      __builtin_amdgcn_s_setprio(0);
      __builtin_amdgcn_sched_barrier(0);
      __builtin_amdgcn_s_barrier();
    }
    // boundary: all waves done reading buf[t&1] -> restage for t+2
    if (t + 2 < TOT) {
      stage(t + 2);
      asm volatile("s_waitcnt vmcnt(8)" ::: "memory");  // t+1 landed (mine)
    } else {
      asm volatile("s_waitcnt vmcnt(0)" ::: "memory");  // tail drain only
    }
    __builtin_amdgcn_s_barrier();
    if ((t % KT) == KT - 1) {
      epi(t / KT, acc);
#pragma unroll
      for (int i = 0; i < 8; ++i)
#pragma unroll
        for (int j = 0; j < 4; ++j) acc[i][j] = (f32x4){0.f, 0.f, 0.f, 0.f};
    }
  }
}

// ---------------- W fp32 -> bf16 ----------------
__global__ __launch_bounds__(256) void k_cvt_w(const float* __restrict__ wq,
                                               const float* __restrict__ wk,
                                               const float* __restrict__ wv,
                                               bf16* __restrict__ out) {
  int i4 = blockIdx.x * 256 + threadIdx.x;
  int m = i4 >> 18;
  int loc = i4 & 262143;
  const float* src = (m == 0) ? wq : (m == 1) ? wk : wv;
  float4 v = reinterpret_cast<const float4*>(src)[loc];
  bf16x4 o;
  o[0] = (bf16)v.x; o[1] = (bf16)v.y; o[2] = (bf16)v.z; o[3] = (bf16)v.w;
  reinterpret_cast<bf16x4*>(out)[i4] = o;
}

// ---------------- LayerNorm -> bf16 ----------------
__global__ __launch_bounds__(256) void k_layernorm(const float* __restrict__ x,
                                                   const float* __restrict__ gamma,
                                                   const float* __restrict__ beta,
                                                   bf16* __restrict__ xn) {
  int row = blockIdx.x;
  int tid = threadIdx.x;
  const float4 v = reinterpret_cast<const float4*>(x + (size_t)row * EMBED)[tid];
  float s = v.x + v.y + v.z + v.w;
  float q = v.x * v.x + v.y * v.y + v.z * v.z + v.w * v.w;
#pragma unroll
  for (int off = 1; off < 64; off <<= 1) {
    s += __shfl_xor(s, off);
    q += __shfl_xor(q, off);
  }
  __shared__ float ls[4], lq[4];
  int w = tid >> 6;
  if ((tid & 63) == 0) { ls[w] = s; lq[w] = q; }
  __syncthreads();
  s = ls[0] + ls[1] + ls[2] + ls[3];
  q = lq[0] + lq[1] + lq[2] + lq[3];
  float mean = s * (1.0f / EMBED);
  float var = q * (1.0f / EMBED) - mean * mean;
  float rstd = rsqrtf(var + 1e-5f);
  float4 gm = reinterpret_cast<const float4*>(gamma)[tid];
  float4 b = reinterpret_cast<const float4*>(beta)[tid];
  bf16x4 o;
  o[0] = (bf16)((v.x - mean) * rstd * gm.x + b.x);
  o[1] = (bf16)((v.y - mean) * rstd * gm.y + b.y);
  o[2] = (bf16)((v.z - mean) * rstd * gm.z + b.z);
  o[3] = (bf16)((v.w - mean) * rstd * gm.w + b.w);
  reinterpret_cast<bf16x4*>(xn + (size_t)row * EMBED)[tid] = o;
}

// ---------------- Fused QKV: M=16384, N=3072 (Q|K|V), 3-sub chain ----------
__global__ __launch_bounds__(512) void k_qkv_chain(const bf16* __restrict__ xn,
                                                   const bf16* __restrict__ wall,
                                                   const float* __restrict__ bq,
                                                   const float* __restrict__ bk,
                                                   const float* __restrict__ bv,
                                                   bf16* __restrict__ qbuf,
                                                   bf16* __restrict__ kbuf,
                                                   bf16* __restrict__ vt) {
  extern __shared__ bf16 smem[];
  const int bid = (int)blockIdx.x;
  const int r = (bid & 7) * 32 + (bid >> 3);  // XCD-bijective: XCD k <- mtiles [8k,8k+8)
  const int ngroup = r & 3, mtile = r >> 2;
  const int tid = (int)threadIdx.x, lane = tid & 63, wid = tid >> 6;
  const int wm = wid >> 2, wn = wid & 3;
  const int cc = lane & 15, g = lane >> 4;
  const bf16* Ab = xn + (size_t)(mtile * 256) * EMBED;
  const bf16* Bb = wall + (size_t)(ngroup * 3 * 256) * EMBED;
  const int r0 = mtile * 256 + wm * 128;

  gemm_chain<3, 16, EMBED, EMBED>(
      Ab, Bb, (size_t)256 * EMBED, smem, [&](int s, f32x4(&acc)[8][4]) {
        const int nt = ngroup * 3 + s;
        const int z = nt >> 2;
        const int col0 = (nt & 3) * 256 + wn * 64;
        if (z < 2) {
          bf16* o = z ? kbuf : qbuf;
          const float* bias = z ? bk : bq;
#pragma unroll
          for (int ni = 0; ni < 4; ++ni) {
            int col = col0 + ni * 16 + cc;
            float bb = bias[col];
#pragma unroll
            for (int mi = 0; mi < 8; ++mi)
#pragma unroll
              for (int j = 0; j < 4; ++j)
                o[(size_t)(r0 + mi * 16 + g * 4 + j) * EMBED + col] =
                    (bf16)(acc[mi][ni][j] + bb);
          }
        } else {
#pragma unroll
          for (int ni = 0; ni < 4; ++ni) {
            int col = col0 + ni * 16 + cc;
            float bb = bv[col];
#pragma unroll
            for (int mi = 0; mi < 8; ++mi) {
              int srow = r0 + mi * 16 + g * 4;
              int b = srow >> 11, sl = srow & (SEQ - 1);
              bf16x4 pk;
#pragma unroll
              for (int j = 0; j < 4; ++j) pk[j] = (bf16)(acc[mi][ni][j] + bb);
              *reinterpret_cast<bf16x4*>(vt + (size_t)b * EMBED * SEQ +
                                         (size_t)col * SEQ + sl) = pk;
            }
          }
        }
      });
}

// ---------------- Scores: exp(QK^T/32) unnorm fp32+bf16, 2-sub chain -------
__global__ __launch_bounds__(512) void k_scores_chain(const bf16* __restrict__ qm,
                                                      const bf16* __restrict__ km,
                                                      float* __restrict__ attn,
                                                      bf16* __restrict__ wbf,
                                                      float* __restrict__ partial) {
  extern __shared__ bf16 smem[];
  const int bid = (int)blockIdx.x;
  const int r = (bid & 7) * 32 + (bid >> 3);  // XCD k <- batch b=k
  const int ngroup = r & 3, mtile = (r >> 2) & 7, b = r >> 5;
  const int tid = (int)threadIdx.x, lane = tid & 63, wid = tid >> 6;
  const int wm = wid >> 2, wn = wid & 3;
  const int cc = lane & 15, g = lane >> 4;
  const bf16* Ab = qm + (size_t)b * SEQ * EMBED + (size_t)(mtile * 256) * EMBED;
  const bf16* Bb = km + (size_t)b * SEQ * EMBED + (size_t)(ngroup * 2 * 256) * EMBED;

  gemm_chain<2, 16, EMBED, EMBED>(
      Ab, Bb, (size_t)256 * EMBED, smem, [&](int s, f32x4(&acc)[8][4]) {
        const int nt = ngroup * 2 + s;
        const int c0 = nt * 256 + wn * 64;
#pragma unroll
        for (int mi = 0; mi < 8; ++mi)
#pragma unroll
          for (int j = 0; j < 4; ++j) {
            size_t grow = (size_t)b * SEQ + mtile * 256 + wm * 128 + mi * 16 + g * 4 + j;
            float ssum = 0.f;
#pragma unroll
            for (int ni = 0; ni < 4; ++ni) {
              float e = __expf(acc[mi][ni][j] * 0.03125f);
              size_t off = grow * SEQ + c0 + ni * 16 + cc;
              attn[off] = e;
              wbf[off] = (bf16)e;
              ssum += e;
            }
            ssum += __shfl_xor(ssum, 1);
            ssum += __shfl_xor(ssum, 2);
            ssum += __shfl_xor(ssum, 4);
            ssum += __shfl_xor(ssum, 8);
            if (cc == 0) partial[grow * 32 + nt * 4 + wn] = ssum;
          }
      });
}

// ---------------- rowsum of 32 partials -> rinv ----------------
__global__ __launch_bounds__(256) void k_rowsum(const float* __restrict__ partial,
                                                float* __restrict__ rinv) {
  int row = blockIdx.x * 256 + threadIdx.x;
  const float4* p = reinterpret_cast<const float4*>(partial + (size_t)row * 32);
  float l = 0.f;
#pragma unroll
  for (int i = 0; i < 8; ++i) {
    float4 v = p[i];
    l += v.x + v.y + v.z + v.w;
  }
  rinv[row] = 1.0f / l;
}

// ---------------- Normalize fp32 attn in-place ----------------
__global__ __launch_bounds__(256) void k_normalize(float* __restrict__ attn,
                                                   const float* __restrict__ rinv) {
  size_t i4 = (size_t)blockIdx.x * 256 + threadIdx.x;
  int row = (int)(i4 >> 9);
  float ri = rinv[row];
  float4 v = reinterpret_cast<float4*>(attn)[i4];
  v.x *= ri; v.y *= ri; v.z *= ri; v.w *= ri;
  reinterpret_cast<float4*>(attn)[i4] = v;
}

// ---------------- PV + rinv + residual, 1-sub chain (K=2048) ---------------
__global__ __launch_bounds__(512) void k_pv_chain(const bf16* __restrict__ wbf,
                                                  const bf16* __restrict__ vt,
                                                  const float* __restrict__ rinv,
                                                  const float* __restrict__ xin,
                                                  float* __restrict__ outp) {
  extern __shared__ bf16 smem[];
  const int bid = (int)blockIdx.x;
  const int r = (bid & 7) * 32 + (bid >> 3);  // XCD k <- batch b=k
  const int ntile = r & 3, mtile = (r >> 2) & 7, b = r >> 5;
  const int tid = (int)threadIdx.x, lane = tid & 63, wid = tid >> 6;
  const int wm = wid >> 2, wn = wid & 3;
  const int cc = lane & 15, g = lane >> 4;
  const bf16* Ab = wbf + (size_t)b * SEQ * SEQ + (size_t)(mtile * 256) * SEQ;
  const bf16* Bb = vt + (size_t)b * EMBED * SEQ + (size_t)(ntile * 256) * SEQ;

  gemm_chain<1, 32, SEQ, SEQ>(
      Ab, Bb, 0, smem, [&](int, f32x4(&acc)[8][4]) {
        const int c0 = ntile * 256 + wn * 64;
#pragma unroll
        for (int mi = 0; mi < 8; ++mi)
#pragma unroll
          for (int j = 0; j < 4; ++j) {
            size_t grow = (size_t)b * SEQ + mtile * 256 + wm * 128 + mi * 16 + g * 4 + j;
            float ri = rinv[grow];
            size_t base = grow * EMBED;
#pragma unroll
            for (int ni = 0; ni < 4; ++ni) {
              size_t off = base + c0 + ni * 16 + cc;
              outp[off] = xin[off] + acc[mi][ni][j] * ri;
            }
          }
      });
}

extern "C" void kernel_launch(void* const* d_in, const int* in_sizes, int n_in,
                              void* d_out, int out_size, void* d_ws, size_t ws_size,
                              hipStream_t stream) {
  const float* x = (const float*)d_in[0];
  const float* Wq = (const float*)d_in[1];
  const float* bq = (const float*)d_in[2];
  const float* Wk = (const float*)d_in[3];
  const float* bk = (const float*)d_in[4];
  const float* Wv = (const float*)d_in[5];
  const float* bv = (const float*)d_in[6];
  const float* gamma = (const float*)d_in[7];
  const float* beta = (const float*)d_in[8];

  float* out = (float*)d_out;
  float* attn = out + (size_t)BATCH * SEQ * EMBED;

  bf16* qbuf = (bf16*)d_out;  // Q,K live in the output region until PV
  bf16* kbuf = qbuf + (size_t)BATCH * SEQ * EMBED;

  // ws: [0,32M) xn | [32M,38M) W bf16 (Wq|Wk|Wv) | later [0,64M) wbf
  //     [64M,96M) Vt | [96M,98M) partial (16384x32 f32) | [98M,+64K) rinv
  bf16* xn = (bf16*)d_ws;
  bf16* wall = xn + (size_t)BATCH * SEQ * EMBED;
  bf16* wbf = (bf16*)d_ws;
  bf16* vt = (bf16*)d_ws + (size_t)BATCH * SEQ * SEQ;
  float* partial = (float*)((char*)d_ws + 100663296ull);
  float* rinv = (float*)((char*)d_ws + 100663296ull + 2097152ull);

  hipFuncSetAttribute((const void*)k_qkv_chain, hipFuncAttributeMaxDynamicSharedMemorySize, 131072);
  hipFuncSetAttribute((const void*)k_scores_chain, hipFuncAttributeMaxDynamicSharedMemorySize, 131072);
  hipFuncSetAttribute((const void*)k_pv_chain, hipFuncAttributeMaxDynamicSharedMemorySize, 131072);

  k_cvt_w<<<3072, 256, 0, stream>>>(Wq, Wk, Wv, wall);
  k_layernorm<<<BATCH * SEQ, 256, 0, stream>>>(x, gamma, beta, xn);
  k_qkv_chain<<<256, 512, 131072, stream>>>(xn, wall, bq, bk, bv, qbuf, kbuf, vt);
  k_scores_chain<<<256, 512, 131072, stream>>>(qbuf, kbuf, attn, wbf, partial);
  k_rowsum<<<64, 256, 0, stream>>>(partial, rinv);
  k_normalize<<<32768, 256, 0, stream>>>(attn, rinv);
  k_pv_chain<<<256, 512, 131072, stream>>>(wbf, vt, rinv, x, out);
}

// Round 5
// 338.362 us; speedup vs baseline: 1.3753x; 1.3753x over previous
//
#include <hip/hip_runtime.h>

#define EMBED 1024
#define SEQ 2048
#define BATCH 8

typedef __bf16 bf16;
typedef bf16 bf16x4 __attribute__((ext_vector_type(4)));
typedef bf16 bf16x8 __attribute__((ext_vector_type(8)));
typedef float f32x4 __attribute__((ext_vector_type(4)));

__device__ __forceinline__ void async_copy16(const bf16* g, bf16* l) {
  __builtin_amdgcn_global_load_lds(
      (const __attribute__((address_space(1))) unsigned int*)g,
      (__attribute__((address_space(3))) unsigned int*)l, 16, 0, 0);
}

// ================= 256x256 BK=64 GEMM core (T2+T3+T4+T5) =================
// Round-2 proven version, verbatim. C = A * B^T, bf16, 512 thr = 8 waves.
template <int KDEPTH, int LDA, int LDB>
__device__ __forceinline__ void gemm_core(const bf16* __restrict__ Ab,
                                          const bf16* __restrict__ Bb,
                                          bf16* lds, f32x4 (&acc)[8][4]) {
  const int tid = (int)threadIdx.x;
  const int lane = tid & 63;
  const int wid = tid >> 6;
  const int wm = wid >> 2, wn = wid & 3;
  const int c = lane & 15, g = lane >> 4;
  const int sx = c & 7;
  constexpr int NT = KDEPTH / 64;

  // linear LDS dest + inverse-swizzled global source (both-sides rule)
  int srow[4], scol[4];
#pragma unroll
  for (int r = 0; r < 4; ++r) {
    int idx = r * 512 + tid;
    srow[r] = idx >> 3;
    scol[r] = ((idx & 7) ^ ((idx >> 3) & 7)) * 8;
  }

  auto stage = [&](int bufsel, int t) {
    bf16* dst = lds + bufsel * 32768;
    const int k0 = t * 64;
#pragma unroll
    for (int r = 0; r < 4; ++r)
      async_copy16(Ab + (size_t)srow[r] * LDA + k0 + scol[r], dst + (r * 512 + tid) * 8);
#pragma unroll
    for (int r = 0; r < 4; ++r)
      async_copy16(Bb + (size_t)srow[r] * LDB + k0 + scol[r], dst + 16384 + (r * 512 + tid) * 8);
  };

  stage(0, 0);
  stage(1, 1);
  asm volatile("s_waitcnt vmcnt(8)" ::: "memory");
  __builtin_amdgcn_s_barrier();

  const int aoffb = (wm * 128 + c) * 64;
  const int boffb = (wn * 64 + c) * 64;

  for (int t = 0; t < NT; ++t) {
    const bf16* bufA = lds + (t & 1) * 32768;
    const bf16* bufB = bufA + 16384;
    bf16x8 bfr[4][2];
#pragma unroll
    for (int p = 0; p < 4; ++p) {
      bf16x8 afr[2][2];
#pragma unroll
      for (int mm = 0; mm < 2; ++mm)
#pragma unroll
        for (int ks = 0; ks < 2; ++ks)
          afr[mm][ks] = *reinterpret_cast<const bf16x8*>(
              bufA + aoffb + (p * 2 + mm) * 1024 + (((ks * 4 + g) ^ sx) * 8));
      if (p == 0) {
#pragma unroll
        for (int ni = 0; ni < 4; ++ni)
#pragma unroll
          for (int ks = 0; ks < 2; ++ks)
            bfr[ni][ks] = *reinterpret_cast<const bf16x8*>(
                bufB + boffb + ni * 1024 + (((ks * 4 + g) ^ sx) * 8));
      }
      __builtin_amdgcn_s_barrier();
      asm volatile("s_waitcnt lgkmcnt(0)" ::: "memory");
      __builtin_amdgcn_sched_barrier(0);
      __builtin_amdgcn_s_setprio(1);
#pragma unroll
      for (int mm = 0; mm < 2; ++mm)
#pragma unroll
        for (int ni = 0; ni < 4; ++ni)
#pragma unroll
          for (int ks = 0; ks < 2; ++ks)
            acc[p * 2 + mm][ni] = __builtin_amdgcn_mfma_f32_16x16x32_bf16(
                afr[mm][ks], bfr[ni][ks], acc[p * 2 + mm][ni], 0, 0, 0);
      __builtin_amdgcn_s_setprio(0);
      __builtin_amdgcn_sched_barrier(0);
      __builtin_amdgcn_s_barrier();
    }
    if (t + 2 < NT) {
      stage(t & 1, t + 2);
      asm volatile("s_waitcnt vmcnt(8)" ::: "memory");
    } else {
      asm volatile("s_waitcnt vmcnt(0)" ::: "memory");
    }
    __builtin_amdgcn_s_barrier();
  }
}

// ------------- fused W-convert + LayerNorm (block-granular split) ---------
__global__ __launch_bounds__(256) void k_pre(const float* __restrict__ x,
                                             const float* __restrict__ gamma,
                                             const float* __restrict__ beta,
                                             const float* __restrict__ wq,
                                             const float* __restrict__ wk,
                                             const float* __restrict__ wv,
                                             bf16* __restrict__ xn,
                                             bf16* __restrict__ wall) {
  const int bid = (int)blockIdx.x;
  const int tid = (int)threadIdx.x;
  if (bid >= BATCH * SEQ) {
    int i4 = (bid - BATCH * SEQ) * 256 + tid;
    int m = i4 >> 18;
    int loc = i4 & 262143;
    const float* src = (m == 0) ? wq : (m == 1) ? wk : wv;
    float4 v = reinterpret_cast<const float4*>(src)[loc];
    bf16x4 o;
    o[0] = (bf16)v.x; o[1] = (bf16)v.y; o[2] = (bf16)v.z; o[3] = (bf16)v.w;
    reinterpret_cast<bf16x4*>(wall)[i4] = o;
    return;
  }
  const int row = bid;
  const float4 v = reinterpret_cast<const float4*>(x + (size_t)row * EMBED)[tid];
  float s = v.x + v.y + v.z + v.w;
  float q = v.x * v.x + v.y * v.y + v.z * v.z + v.w * v.w;
#pragma unroll
  for (int off = 1; off < 64; off <<= 1) {
    s += __shfl_xor(s, off);
    q += __shfl_xor(q, off);
  }
  __shared__ float ls[4], lq[4];
  int w = tid >> 6;
  if ((tid & 63) == 0) { ls[w] = s; lq[w] = q; }
  __syncthreads();
  s = ls[0] + ls[1] + ls[2] + ls[3];
  q = lq[0] + lq[1] + lq[2] + lq[3];
  float mean = s * (1.0f / EMBED);
  float var = q * (1.0f / EMBED) - mean * mean;
  float rstd = rsqrtf(var + 1e-5f);
  float4 gm = reinterpret_cast<const float4*>(gamma)[tid];
  float4 b = reinterpret_cast<const float4*>(beta)[tid];
  bf16x4 o;
  o[0] = (bf16)((v.x - mean) * rstd * gm.x + b.x);
  o[1] = (bf16)((v.y - mean) * rstd * gm.y + b.y);
  o[2] = (bf16)((v.z - mean) * rstd * gm.z + b.z);
  o[3] = (bf16)((v.w - mean) * rstd * gm.w + b.w);
  reinterpret_cast<bf16x4*>(xn + (size_t)row * EMBED)[tid] = o;
}

// ---------------- QKV projection (round-2 verbatim) ----------------
__global__ __launch_bounds__(512) void k_qkv256(const bf16* __restrict__ xn,
                                                const bf16* __restrict__ wall,
                                                const float* __restrict__ bq,
                                                const float* __restrict__ bk,
                                                const float* __restrict__ bv,
                                                bf16* __restrict__ qbuf,
                                                bf16* __restrict__ kbuf,
                                                bf16* __restrict__ vt) {
  extern __shared__ bf16 smem[];
  const int ntile = blockIdx.x, mtile = blockIdx.y, z = blockIdx.z;
  const int tid = (int)threadIdx.x, lane = tid & 63, wid = tid >> 6;
  const int wm = wid >> 2, wn = wid & 3;
  const int cc = lane & 15, g = lane >> 4;
  const bf16* Ab = xn + (size_t)(mtile * 256) * EMBED;
  const bf16* Bb = wall + (size_t)z * EMBED * EMBED + (size_t)(ntile * 256) * EMBED;
  f32x4 acc[8][4];
#pragma unroll
  for (int i = 0; i < 8; ++i)
#pragma unroll
    for (int j = 0; j < 4; ++j) acc[i][j] = (f32x4){0.f, 0.f, 0.f, 0.f};
  gemm_core<EMBED, EMBED, EMBED>(Ab, Bb, smem, acc);

  const int c0 = ntile * 256 + wn * 64;
  const int r0 = mtile * 256 + wm * 128;
  if (z < 2) {
    bf16* o = z ? kbuf : qbuf;
    const float* bias = z ? bk : bq;
#pragma unroll
    for (int mi = 0; mi < 8; ++mi)
#pragma unroll
      for (int ni = 0; ni < 4; ++ni) {
        int col = c0 + ni * 16 + cc;
        float bb = bias[col];
#pragma unroll
        for (int j = 0; j < 4; ++j)
          o[(size_t)(r0 + mi * 16 + g * 4 + j) * EMBED + col] = (bf16)(acc[mi][ni][j] + bb);
      }
  } else {
#pragma unroll
    for (int mi = 0; mi < 8; ++mi) {
      int srow = r0 + mi * 16 + g * 4;
      int b = srow >> 11, sl = srow & (SEQ - 1);
#pragma unroll
      for (int ni = 0; ni < 4; ++ni) {
        int col = c0 + ni * 16 + cc;
        float bb = bv[col];
        bf16x4 pk;
#pragma unroll
        for (int j = 0; j < 4; ++j) pk[j] = (bf16)(acc[mi][ni][j] + bb);
        *reinterpret_cast<bf16x4*>(vt + (size_t)b * EMBED * SEQ + (size_t)col * SEQ + sl) = pk;
      }
    }
  }
}

// ------- Scores: exp(QK^T/32) -> bf16 wbf only + per-row partials --------
__global__ __launch_bounds__(512) void k_scores256(const bf16* __restrict__ qm,
                                                   const bf16* __restrict__ km,
                                                   bf16* __restrict__ wbf,
                                                   float* __restrict__ partial) {
  extern __shared__ bf16 smem[];
  const int ntile = blockIdx.x, mtile = blockIdx.y, bb = blockIdx.z;
  const int tid = (int)threadIdx.x, lane = tid & 63, wid = tid >> 6;
  const int wm = wid >> 2, wn = wid & 3;
  const int cc = lane & 15, g = lane >> 4;
  const bf16* Ab = qm + (size_t)bb * SEQ * EMBED + (size_t)(mtile * 256) * EMBED;
  const bf16* Bb = km + (size_t)bb * SEQ * EMBED + (size_t)(ntile * 256) * EMBED;
  f32x4 acc[8][4];
#pragma unroll
  for (int i = 0; i < 8; ++i)
#pragma unroll
    for (int j = 0; j < 4; ++j) acc[i][j] = (f32x4){0.f, 0.f, 0.f, 0.f};
  gemm_core<EMBED, EMBED, EMBED>(Ab, Bb, smem, acc);

  float* red = (float*)smem;  // 256 rows x 4 waveN
  const int c0 = ntile * 256 + wn * 64;
#pragma unroll
  for (int mi = 0; mi < 8; ++mi) {
#pragma unroll
    for (int j = 0; j < 4; ++j) {
      int lrow = wm * 128 + mi * 16 + g * 4 + j;
      size_t grow = (size_t)bb * SEQ + mtile * 256 + lrow;
      float s = 0.f;
#pragma unroll
      for (int ni = 0; ni < 4; ++ni) {
        float e = __expf(acc[mi][ni][j] * 0.03125f);
        wbf[grow * SEQ + c0 + ni * 16 + cc] = (bf16)e;
        s += e;
      }
      s += __shfl_xor(s, 1);
      s += __shfl_xor(s, 2);
      s += __shfl_xor(s, 4);
      s += __shfl_xor(s, 8);
      if (cc == 0) red[lrow * 4 + wn] = s;
    }
  }
  __syncthreads();
  if (tid < 256) {
    float l = red[tid * 4 + 0] + red[tid * 4 + 1] + red[tid * 4 + 2] + red[tid * 4 + 3];
    partial[((size_t)bb * SEQ + mtile * 256 + tid) * 8 + ntile] = l;
  }
}

// ---------------- rowsum -> rinv ----------------
__global__ __launch_bounds__(256) void k_rowsum(const float* __restrict__ partial,
                                                float* __restrict__ rinv) {
  int row = blockIdx.x * 256 + threadIdx.x;
  const float* p = partial + (size_t)row * 8;
  float l = 0.f;
#pragma unroll
  for (int i = 0; i < 8; ++i) l += p[i];
  rinv[row] = 1.0f / l;
}

// ---------------- PV (round-2 verbatim) + rinv + residual ----------------
__global__ __launch_bounds__(512) void k_pv256(const bf16* __restrict__ wbf,
                                               const bf16* __restrict__ vt,
                                               const float* __restrict__ rinv,
                                               const float* __restrict__ xin,
                                               float* __restrict__ outp) {
  extern __shared__ bf16 smem[];
  const int ntile = blockIdx.x, mtile = blockIdx.y, bb = blockIdx.z;
  const int tid = (int)threadIdx.x, lane = tid & 63, wid = tid >> 6;
  const int wm = wid >> 2, wn = wid & 3;
  const int cc = lane & 15, g = lane >> 4;
  const bf16* Ab = wbf + (size_t)bb * SEQ * SEQ + (size_t)(mtile * 256) * SEQ;
  const bf16* Bb = vt + (size_t)bb * EMBED * SEQ + (size_t)(ntile * 256) * SEQ;
  f32x4 acc[8][4];
#pragma unroll
  for (int i = 0; i < 8; ++i)
#pragma unroll
    for (int j = 0; j < 4; ++j) acc[i][j] = (f32x4){0.f, 0.f, 0.f, 0.f};
  gemm_core<SEQ, SEQ, SEQ>(Ab, Bb, smem, acc);

  const int c0 = ntile * 256 + wn * 64;
#pragma unroll
  for (int mi = 0; mi < 8; ++mi) {
#pragma unroll
    for (int j = 0; j < 4; ++j) {
      size_t grow = (size_t)bb * SEQ + mtile * 256 + wm * 128 + mi * 16 + g * 4 + j;
      float ri = rinv[grow];
      size_t base = grow * EMBED;
#pragma unroll
      for (int ni = 0; ni < 4; ++ni) {
        size_t off = base + c0 + ni * 16 + cc;
        outp[off] = xin[off] + acc[mi][ni][j] * ri;
      }
    }
  }
}

// -------- normalize: attn_fp32 = bf16(exp) * rinv  (192 MB pass) ---------
// 33554432 bf16 / 8-per-chunk = 4194304 chunks -> grid 16384 x 256
__global__ __launch_bounds__(256) void k_norm_bf(const bf16* __restrict__ wbf,
                                                 const float* __restrict__ rinv,
                                                 float* __restrict__ attn) {
  size_t i8 = (size_t)blockIdx.x * 256 + threadIdx.x;
  int row = (int)(i8 >> 8);  // 256 chunks per 2048-elem row
  float ri = rinv[row];
  bf16x8 v = reinterpret_cast<const bf16x8*>(wbf)[i8];
  float4 lo, hi;
  lo.x = (float)v[0] * ri; lo.y = (float)v[1] * ri;
  lo.z = (float)v[2] * ri; lo.w = (float)v[3] * ri;
  hi.x = (float)v[4] * ri; hi.y = (float)v[5] * ri;
  hi.z = (float)v[6] * ri; hi.w = (float)v[7] * ri;
  reinterpret_cast<float4*>(attn)[i8 * 2] = lo;
  reinterpret_cast<float4*>(attn)[i8 * 2 + 1] = hi;
}

extern "C" void kernel_launch(void* const* d_in, const int* in_sizes, int n_in,
                              void* d_out, int out_size, void* d_ws, size_t ws_size,
                              hipStream_t stream) {
  const float* x = (const float*)d_in[0];
  const float* Wq = (const float*)d_in[1];
  const float* bq = (const float*)d_in[2];
  const float* Wk = (const float*)d_in[3];
  const float* bk = (const float*)d_in[4];
  const float* Wv = (const float*)d_in[5];
  const float* bv = (const float*)d_in[6];
  const float* gamma = (const float*)d_in[7];
  const float* beta = (const float*)d_in[8];

  float* out = (float*)d_out;
  float* attn = out + (size_t)BATCH * SEQ * EMBED;

  bf16* qbuf = (bf16*)d_out;  // Q,K live in the output region until PV
  bf16* kbuf = qbuf + (size_t)BATCH * SEQ * EMBED;

  // ws: [0,32M) xn | [32M,38M) W bf16 | later [0,64M) wbf | [64M,96M) Vt
  //     [96M,96.5M) partial (16384x8 f32) | [96.5M,+64K) rinv
  bf16* xn = (bf16*)d_ws;
  bf16* wall = xn + (size_t)BATCH * SEQ * EMBED;
  bf16* wbf = (bf16*)d_ws;
  bf16* vt = (bf16*)d_ws + (size_t)BATCH * SEQ * SEQ;
  float* partial = (float*)((char*)d_ws + 100663296ull);
  float* rinv = (float*)((char*)d_ws + 100663296ull + 524288ull);

  hipFuncSetAttribute((const void*)k_qkv256, hipFuncAttributeMaxDynamicSharedMemorySize, 131072);
  hipFuncSetAttribute((const void*)k_scores256, hipFuncAttributeMaxDynamicSharedMemorySize, 131072);
  hipFuncSetAttribute((const void*)k_pv256, hipFuncAttributeMaxDynamicSharedMemorySize, 131072);

  k_pre<<<BATCH * SEQ + 3072, 256, 0, stream>>>(x, gamma, beta, Wq, Wk, Wv, xn, wall);
  k_qkv256<<<dim3(4, 64, 3), 512, 131072, stream>>>(xn, wall, bq, bk, bv, qbuf, kbuf, vt);
  k_scores256<<<dim3(8, 8, 8), 512, 131072, stream>>>(qbuf, kbuf, wbf, partial);
  k_rowsum<<<64, 256, 0, stream>>>(partial, rinv);
  k_pv256<<<dim3(4, 8, 8), 512, 131072, stream>>>(wbf, vt, rinv, x, out);
  k_norm_bf<<<16384, 256, 0, stream>>>(wbf, rinv, attn);
}

// Round 6
// 319.444 us; speedup vs baseline: 1.4567x; 1.0592x over previous
//
#include <hip/hip_runtime.h>

#define EMBED 1024
#define SEQ 2048
#define BATCH 8

typedef __bf16 bf16;
typedef bf16 bf16x4 __attribute__((ext_vector_type(4)));
typedef bf16 bf16x8 __attribute__((ext_vector_type(8)));
typedef float f32x4 __attribute__((ext_vector_type(4)));

__device__ __forceinline__ void async_copy16(const bf16* g, bf16* l) {
  __builtin_amdgcn_global_load_lds(
      (const __attribute__((address_space(1))) unsigned int*)g,
      (__attribute__((address_space(3))) unsigned int*)l, 16, 0, 0);
}

// ================= 256x256 BK=64 GEMM core (T2+T3+T4+T5) =================
// Round-2 proven version, verbatim. C = A * B^T, bf16, 512 thr = 8 waves.
template <int KDEPTH, int LDA, int LDB>
__device__ __forceinline__ void gemm_core(const bf16* __restrict__ Ab,
                                          const bf16* __restrict__ Bb,
                                          bf16* lds, f32x4 (&acc)[8][4]) {
  const int tid = (int)threadIdx.x;
  const int lane = tid & 63;
  const int wid = tid >> 6;
  const int wm = wid >> 2, wn = wid & 3;
  const int c = lane & 15, g = lane >> 4;
  const int sx = c & 7;
  constexpr int NT = KDEPTH / 64;

  // linear LDS dest + inverse-swizzled global source (both-sides rule)
  int srow[4], scol[4];
#pragma unroll
  for (int r = 0; r < 4; ++r) {
    int idx = r * 512 + tid;
    srow[r] = idx >> 3;
    scol[r] = ((idx & 7) ^ ((idx >> 3) & 7)) * 8;
  }

  auto stage = [&](int bufsel, int t) {
    bf16* dst = lds + bufsel * 32768;
    const int k0 = t * 64;
#pragma unroll
    for (int r = 0; r < 4; ++r)
      async_copy16(Ab + (size_t)srow[r] * LDA + k0 + scol[r], dst + (r * 512 + tid) * 8);
#pragma unroll
    for (int r = 0; r < 4; ++r)
      async_copy16(Bb + (size_t)srow[r] * LDB + k0 + scol[r], dst + 16384 + (r * 512 + tid) * 8);
  };

  stage(0, 0);
  stage(1, 1);
  asm volatile("s_waitcnt vmcnt(8)" ::: "memory");
  __builtin_amdgcn_s_barrier();

  const int aoffb = (wm * 128 + c) * 64;
  const int boffb = (wn * 64 + c) * 64;

  for (int t = 0; t < NT; ++t) {
    const bf16* bufA = lds + (t & 1) * 32768;
    const bf16* bufB = bufA + 16384;
    bf16x8 bfr[4][2];
#pragma unroll
    for (int p = 0; p < 4; ++p) {
      bf16x8 afr[2][2];
#pragma unroll
      for (int mm = 0; mm < 2; ++mm)
#pragma unroll
        for (int ks = 0; ks < 2; ++ks)
          afr[mm][ks] = *reinterpret_cast<const bf16x8*>(
              bufA + aoffb + (p * 2 + mm) * 1024 + (((ks * 4 + g) ^ sx) * 8));
      if (p == 0) {
#pragma unroll
        for (int ni = 0; ni < 4; ++ni)
#pragma unroll
          for (int ks = 0; ks < 2; ++ks)
            bfr[ni][ks] = *reinterpret_cast<const bf16x8*>(
                bufB + boffb + ni * 1024 + (((ks * 4 + g) ^ sx) * 8));
      }
      __builtin_amdgcn_s_barrier();
      asm volatile("s_waitcnt lgkmcnt(0)" ::: "memory");
      __builtin_amdgcn_sched_barrier(0);
      __builtin_amdgcn_s_setprio(1);
#pragma unroll
      for (int mm = 0; mm < 2; ++mm)
#pragma unroll
        for (int ni = 0; ni < 4; ++ni)
#pragma unroll
          for (int ks = 0; ks < 2; ++ks)
            acc[p * 2 + mm][ni] = __builtin_amdgcn_mfma_f32_16x16x32_bf16(
                afr[mm][ks], bfr[ni][ks], acc[p * 2 + mm][ni], 0, 0, 0);
      __builtin_amdgcn_s_setprio(0);
      __builtin_amdgcn_sched_barrier(0);
      __builtin_amdgcn_s_barrier();
    }
    if (t + 2 < NT) {
      stage(t & 1, t + 2);
      asm volatile("s_waitcnt vmcnt(8)" ::: "memory");
    } else {
      asm volatile("s_waitcnt vmcnt(0)" ::: "memory");
    }
    __builtin_amdgcn_s_barrier();
  }
}

// ------------- fused W-convert + LayerNorm (block-granular split) ---------
__global__ __launch_bounds__(256) void k_pre(const float* __restrict__ x,
                                             const float* __restrict__ gamma,
                                             const float* __restrict__ beta,
                                             const float* __restrict__ wq,
                                             const float* __restrict__ wk,
                                             const float* __restrict__ wv,
                                             bf16* __restrict__ xn,
                                             bf16* __restrict__ wall) {
  const int bid = (int)blockIdx.x;
  const int tid = (int)threadIdx.x;
  if (bid >= BATCH * SEQ) {
    int i4 = (bid - BATCH * SEQ) * 256 + tid;
    int m = i4 >> 18;
    int loc = i4 & 262143;
    const float* src = (m == 0) ? wq : (m == 1) ? wk : wv;
    float4 v = reinterpret_cast<const float4*>(src)[loc];
    bf16x4 o;
    o[0] = (bf16)v.x; o[1] = (bf16)v.y; o[2] = (bf16)v.z; o[3] = (bf16)v.w;
    reinterpret_cast<bf16x4*>(wall)[i4] = o;
    return;
  }
  const int row = bid;
  const float4 v = reinterpret_cast<const float4*>(x + (size_t)row * EMBED)[tid];
  float s = v.x + v.y + v.z + v.w;
  float q = v.x * v.x + v.y * v.y + v.z * v.z + v.w * v.w;
#pragma unroll
  for (int off = 1; off < 64; off <<= 1) {
    s += __shfl_xor(s, off);
    q += __shfl_xor(q, off);
  }
  __shared__ float ls[4], lq[4];
  int w = tid >> 6;
  if ((tid & 63) == 0) { ls[w] = s; lq[w] = q; }
  __syncthreads();
  s = ls[0] + ls[1] + ls[2] + ls[3];
  q = lq[0] + lq[1] + lq[2] + lq[3];
  float mean = s * (1.0f / EMBED);
  float var = q * (1.0f / EMBED) - mean * mean;
  float rstd = rsqrtf(var + 1e-5f);
  float4 gm = reinterpret_cast<const float4*>(gamma)[tid];
  float4 b = reinterpret_cast<const float4*>(beta)[tid];
  bf16x4 o;
  o[0] = (bf16)((v.x - mean) * rstd * gm.x + b.x);
  o[1] = (bf16)((v.y - mean) * rstd * gm.y + b.y);
  o[2] = (bf16)((v.z - mean) * rstd * gm.z + b.z);
  o[3] = (bf16)((v.w - mean) * rstd * gm.w + b.w);
  reinterpret_cast<bf16x4*>(xn + (size_t)row * EMBED)[tid] = o;
}

// ---------------- QKV projection, XCD-chunked 1D grid (768) ----------------
// hw block h: xcd=h&7, pos=h>>3; z=pos>>5, mtile=xcd*8+((pos>>2)&7), nt=pos&3.
// Each XCD owns mtiles [8k,8k+8): A-panels stay L2-resident; each 256-block
// dispatch round covers exactly one z (one W matrix).
__global__ __launch_bounds__(512) void k_qkv256(const bf16* __restrict__ xn,
                                                const bf16* __restrict__ wall,
                                                const float* __restrict__ bq,
                                                const float* __restrict__ bk,
                                                const float* __restrict__ bv,
                                                bf16* __restrict__ qbuf,
                                                bf16* __restrict__ kbuf,
                                                bf16* __restrict__ vt) {
  extern __shared__ bf16 smem[];
  const int h = (int)blockIdx.x;
  const int xcd = h & 7, pos = h >> 3;
  const int z = pos >> 5;
  const int mtile = xcd * 8 + ((pos >> 2) & 7);
  const int ntile = pos & 3;
  const int tid = (int)threadIdx.x, lane = tid & 63, wid = tid >> 6;
  const int wm = wid >> 2, wn = wid & 3;
  const int cc = lane & 15, g = lane >> 4;
  const bf16* Ab = xn + (size_t)(mtile * 256) * EMBED;
  const bf16* Bb = wall + (size_t)z * EMBED * EMBED + (size_t)(ntile * 256) * EMBED;
  f32x4 acc[8][4];
#pragma unroll
  for (int i = 0; i < 8; ++i)
#pragma unroll
    for (int j = 0; j < 4; ++j) acc[i][j] = (f32x4){0.f, 0.f, 0.f, 0.f};
  gemm_core<EMBED, EMBED, EMBED>(Ab, Bb, smem, acc);

  const int c0 = ntile * 256 + wn * 64;
  const int r0 = mtile * 256 + wm * 128;
  if (z < 2) {
    bf16* o = z ? kbuf : qbuf;
    const float* bias = z ? bk : bq;
#pragma unroll
    for (int mi = 0; mi < 8; ++mi)
#pragma unroll
      for (int ni = 0; ni < 4; ++ni) {
        int col = c0 + ni * 16 + cc;
        float bb = bias[col];
#pragma unroll
        for (int j = 0; j < 4; ++j)
          o[(size_t)(r0 + mi * 16 + g * 4 + j) * EMBED + col] = (bf16)(acc[mi][ni][j] + bb);
      }
  } else {
#pragma unroll
    for (int mi = 0; mi < 8; ++mi) {
      int srow = r0 + mi * 16 + g * 4;
      int b = srow >> 11, sl = srow & (SEQ - 1);
#pragma unroll
      for (int ni = 0; ni < 4; ++ni) {
        int col = c0 + ni * 16 + cc;
        float bb = bv[col];
        bf16x4 pk;
#pragma unroll
        for (int j = 0; j < 4; ++j) pk[j] = (bf16)(acc[mi][ni][j] + bb);
        *reinterpret_cast<bf16x4*>(vt + (size_t)b * EMBED * SEQ + (size_t)col * SEQ + sl) = pk;
      }
    }
  }
}

// ------- Scores: XCD-chunked 1D grid (512); XCD k <- batch k ----------
__global__ __launch_bounds__(512) void k_scores256(const bf16* __restrict__ qm,
                                                   const bf16* __restrict__ km,
                                                   bf16* __restrict__ wbf,
                                                   float* __restrict__ partial) {
  extern __shared__ bf16 smem[];
  const int h = (int)blockIdx.x;
  const int bb = h & 7, pos = h >> 3;
  const int mtile = pos >> 3, ntile = pos & 7;
  const int tid = (int)threadIdx.x, lane = tid & 63, wid = tid >> 6;
  const int wm = wid >> 2, wn = wid & 3;
  const int cc = lane & 15, g = lane >> 4;
  const bf16* Ab = qm + (size_t)bb * SEQ * EMBED + (size_t)(mtile * 256) * EMBED;
  const bf16* Bb = km + (size_t)bb * SEQ * EMBED + (size_t)(ntile * 256) * EMBED;
  f32x4 acc[8][4];
#pragma unroll
  for (int i = 0; i < 8; ++i)
#pragma unroll
    for (int j = 0; j < 4; ++j) acc[i][j] = (f32x4){0.f, 0.f, 0.f, 0.f};
  gemm_core<EMBED, EMBED, EMBED>(Ab, Bb, smem, acc);

  float* red = (float*)smem;  // 256 rows x 4 waveN
  const int c0 = ntile * 256 + wn * 64;
#pragma unroll
  for (int mi = 0; mi < 8; ++mi) {
#pragma unroll
    for (int j = 0; j < 4; ++j) {
      int lrow = wm * 128 + mi * 16 + g * 4 + j;
      size_t grow = (size_t)bb * SEQ + mtile * 256 + lrow;
      float s = 0.f;
#pragma unroll
      for (int ni = 0; ni < 4; ++ni) {
        float e = __expf(acc[mi][ni][j] * 0.03125f);
        wbf[grow * SEQ + c0 + ni * 16 + cc] = (bf16)e;
        s += e;
      }
      s += __shfl_xor(s, 1);
      s += __shfl_xor(s, 2);
      s += __shfl_xor(s, 4);
      s += __shfl_xor(s, 8);
      if (cc == 0) red[lrow * 4 + wn] = s;
    }
  }
  __syncthreads();
  if (tid < 256) {
    float l = red[tid * 4 + 0] + red[tid * 4 + 1] + red[tid * 4 + 2] + red[tid * 4 + 3];
    partial[((size_t)bb * SEQ + mtile * 256 + tid) * 8 + ntile] = l;
  }
}

// ---------------- rowsum -> rinv ----------------
__global__ __launch_bounds__(256) void k_rowsum(const float* __restrict__ partial,
                                                float* __restrict__ rinv) {
  int row = blockIdx.x * 256 + threadIdx.x;
  const float* p = partial + (size_t)row * 8;
  float l = 0.f;
#pragma unroll
  for (int i = 0; i < 8; ++i) l += p[i];
  rinv[row] = 1.0f / l;
}

// ------- PV: XCD-chunked 1D grid (256); XCD k <- batch k + rinv + residual --
__global__ __launch_bounds__(512) void k_pv256(const bf16* __restrict__ wbf,
                                               const bf16* __restrict__ vt,
                                               const float* __restrict__ rinv,
                                               const float* __restrict__ xin,
                                               float* __restrict__ outp) {
  extern __shared__ bf16 smem[];
  const int h = (int)blockIdx.x;
  const int bb = h & 7, pos = h >> 3;
  const int mtile = pos >> 2, ntile = pos & 3;
  const int tid = (int)threadIdx.x, lane = tid & 63, wid = tid >> 6;
  const int wm = wid >> 2, wn = wid & 3;
  const int cc = lane & 15, g = lane >> 4;
  const bf16* Ab = wbf + (size_t)bb * SEQ * SEQ + (size_t)(mtile * 256) * SEQ;
  const bf16* Bb = vt + (size_t)bb * EMBED * SEQ + (size_t)(ntile * 256) * SEQ;
  f32x4 acc[8][4];
#pragma unroll
  for (int i = 0; i < 8; ++i)
#pragma unroll
    for (int j = 0; j < 4; ++j) acc[i][j] = (f32x4){0.f, 0.f, 0.f, 0.f};
  gemm_core<SEQ, SEQ, SEQ>(Ab, Bb, smem, acc);

  const int c0 = ntile * 256 + wn * 64;
#pragma unroll
  for (int mi = 0; mi < 8; ++mi) {
#pragma unroll
    for (int j = 0; j < 4; ++j) {
      size_t grow = (size_t)bb * SEQ + mtile * 256 + wm * 128 + mi * 16 + g * 4 + j;
      float ri = rinv[grow];
      size_t base = grow * EMBED;
#pragma unroll
      for (int ni = 0; ni < 4; ++ni) {
        size_t off = base + c0 + ni * 16 + cc;
        outp[off] = xin[off] + acc[mi][ni][j] * ri;
      }
    }
  }
}

// -------- normalize: attn_fp32 = bf16(exp) * rinv  (192 MB pass) ---------
// 33554432 bf16 / 8-per-chunk = 4194304 chunks -> grid 16384 x 256
__global__ __launch_bounds__(256) void k_norm_bf(const bf16* __restrict__ wbf,
                                                 const float* __restrict__ rinv,
                                                 float* __restrict__ attn) {
  size_t i8 = (size_t)blockIdx.x * 256 + threadIdx.x;
  int row = (int)(i8 >> 8);  // 256 chunks per 2048-elem row
  float ri = rinv[row];
  bf16x8 v = reinterpret_cast<const bf16x8*>(wbf)[i8];
  float4 lo, hi;
  lo.x = (float)v[0] * ri; lo.y = (float)v[1] * ri;
  lo.z = (float)v[2] * ri; lo.w = (float)v[3] * ri;
  hi.x = (float)v[4] * ri; hi.y = (float)v[5] * ri;
  hi.z = (float)v[6] * ri; hi.w = (float)v[7] * ri;
  reinterpret_cast<float4*>(attn)[i8 * 2] = lo;
  reinterpret_cast<float4*>(attn)[i8 * 2 + 1] = hi;
}

extern "C" void kernel_launch(void* const* d_in, const int* in_sizes, int n_in,
                              void* d_out, int out_size, void* d_ws, size_t ws_size,
                              hipStream_t stream) {
  const float* x = (const float*)d_in[0];
  const float* Wq = (const float*)d_in[1];
  const float* bq = (const float*)d_in[2];
  const float* Wk = (const float*)d_in[3];
  const float* bk = (const float*)d_in[4];
  const float* Wv = (const float*)d_in[5];
  const float* bv = (const float*)d_in[6];
  const float* gamma = (const float*)d_in[7];
  const float* beta = (const float*)d_in[8];

  float* out = (float*)d_out;
  float* attn = out + (size_t)BATCH * SEQ * EMBED;

  bf16* qbuf = (bf16*)d_out;  // Q,K live in the output region until PV
  bf16* kbuf = qbuf + (size_t)BATCH * SEQ * EMBED;

  // ws: [0,32M) xn | [32M,38M) W bf16 | later [0,64M) wbf | [64M,96M) Vt
  //     [96M,96.5M) partial (16384x8 f32) | [96.5M,+64K) rinv
  bf16* xn = (bf16*)d_ws;
  bf16* wall = xn + (size_t)BATCH * SEQ * EMBED;
  bf16* wbf = (bf16*)d_ws;
  bf16* vt = (bf16*)d_ws + (size_t)BATCH * SEQ * SEQ;
  float* partial = (float*)((char*)d_ws + 100663296ull);
  float* rinv = (float*)((char*)d_ws + 100663296ull + 524288ull);

  hipFuncSetAttribute((const void*)k_qkv256, hipFuncAttributeMaxDynamicSharedMemorySize, 131072);
  hipFuncSetAttribute((const void*)k_scores256, hipFuncAttributeMaxDynamicSharedMemorySize, 131072);
  hipFuncSetAttribute((const void*)k_pv256, hipFuncAttributeMaxDynamicSharedMemorySize, 131072);

  k_pre<<<BATCH * SEQ + 3072, 256, 0, stream>>>(x, gamma, beta, Wq, Wk, Wv, xn, wall);
  k_qkv256<<<768, 512, 131072, stream>>>(xn, wall, bq, bk, bv, qbuf, kbuf, vt);
  k_scores256<<<512, 512, 131072, stream>>>(qbuf, kbuf, wbf, partial);
  k_rowsum<<<64, 256, 0, stream>>>(partial, rinv);
  k_pv256<<<256, 512, 131072, stream>>>(wbf, vt, rinv, x, out);
  k_norm_bf<<<16384, 256, 0, stream>>>(wbf, rinv, attn);
}

// Round 7
// 307.799 us; speedup vs baseline: 1.5118x; 1.0378x over previous
//
#include <hip/hip_runtime.h>

#define EMBED 1024
#define SEQ 2048
#define BATCH 8

typedef __bf16 bf16;
typedef bf16 bf16x4 __attribute__((ext_vector_type(4)));
typedef bf16 bf16x8 __attribute__((ext_vector_type(8)));
typedef float f32x4 __attribute__((ext_vector_type(4)));

__device__ __forceinline__ void async_copy16(const bf16* g, bf16* l) {
  __builtin_amdgcn_global_load_lds(
      (const __attribute__((address_space(1))) unsigned int*)g,
      (__attribute__((address_space(3))) unsigned int*)l, 16, 0, 0);
}

// ================= 256x256 BK=64 GEMM core, phase-pipelined =================
// C = A * B^T, bf16, 512 thr = 8 waves (2M x 4N), per-wave 128x64 out.
// LDS: 2 x (A 256x64 + B 256x64) = 128 KiB, XOR-swizzled 16B slots.
// ds_read ISSUE runs one phase ahead of MFMA consumption (afr ping-pong),
// so lgkmcnt waits are covered by the previous MFMA cluster.
template <int KDEPTH, int LDA, int LDB>
__device__ __forceinline__ void gemm_core(const bf16* __restrict__ Ab,
                                          const bf16* __restrict__ Bb,
                                          bf16* lds, f32x4 (&acc)[8][4]) {
  const int tid = (int)threadIdx.x;
  const int lane = tid & 63;
  const int wid = tid >> 6;
  const int wm = wid >> 2, wn = wid & 3;
  const int c = lane & 15, g = lane >> 4;
  const int sx = c & 7;
  constexpr int NT = KDEPTH / 64;

  // linear LDS dest + inverse-swizzled global source (both-sides rule)
  int srow[4], scol[4];
#pragma unroll
  for (int r = 0; r < 4; ++r) {
    int idx = r * 512 + tid;
    srow[r] = idx >> 3;
    scol[r] = ((idx & 7) ^ ((idx >> 3) & 7)) * 8;
  }

  auto stage = [&](int bufsel, int t) {
    bf16* dst = lds + bufsel * 32768;
    const int k0 = t * 64;
#pragma unroll
    for (int r = 0; r < 4; ++r)
      async_copy16(Ab + (size_t)srow[r] * LDA + k0 + scol[r], dst + (r * 512 + tid) * 8);
#pragma unroll
    for (int r = 0; r < 4; ++r)
      async_copy16(Bb + (size_t)srow[r] * LDB + k0 + scol[r], dst + 16384 + (r * 512 + tid) * 8);
  };

  stage(0, 0);
  stage(1, 1);
  asm volatile("s_waitcnt vmcnt(8)" ::: "memory");  // tile 0 landed (mine)
  __builtin_amdgcn_s_barrier();                     // tile 0 landed (everyone)

  const int aoffb = (wm * 128 + c) * 64;
  const int boffb = (wn * 64 + c) * 64;

  bf16x8 afr[2][2][2];  // [pipe][mm][ks]
  bf16x8 bfr[4][2];     // per-tile B fragments

  // prologue: issue (t=0, p=0) A-frags + tile-0 B-frags (12 ds_reads)
#pragma unroll
  for (int mm = 0; mm < 2; ++mm)
#pragma unroll
    for (int ks = 0; ks < 2; ++ks)
      afr[0][mm][ks] = *reinterpret_cast<const bf16x8*>(
          lds + aoffb + mm * 1024 + (((ks * 4 + g) ^ sx) * 8));
#pragma unroll
  for (int ni = 0; ni < 4; ++ni)
#pragma unroll
    for (int ks = 0; ks < 2; ++ks)
      bfr[ni][ks] = *reinterpret_cast<const bf16x8*>(
          lds + 16384 + boffb + ni * 1024 + (((ks * 4 + g) ^ sx) * 8));
  __builtin_amdgcn_sched_barrier(0);

  for (int t = 0; t < NT; ++t) {
    const bf16* cA = lds + (t & 1) * 32768;
    const bf16* nA = lds + ((t + 1) & 1) * 32768;
    const bf16* nB = nA + 16384;

#pragma unroll
    for (int p = 0; p < 3; ++p) {
      // issue NEXT phase's A-frags (consumed at p+1)
#pragma unroll
      for (int mm = 0; mm < 2; ++mm)
#pragma unroll
        for (int ks = 0; ks < 2; ++ks)
          afr[(p + 1) & 1][mm][ks] = *reinterpret_cast<const bf16x8*>(
              cA + aoffb + ((p + 1) * 2 + mm) * 1024 + (((ks * 4 + g) ^ sx) * 8));
      __builtin_amdgcn_s_barrier();
      asm volatile("s_waitcnt lgkmcnt(4)" ::: "memory");  // current frags landed
      __builtin_amdgcn_sched_barrier(0);
      __builtin_amdgcn_s_setprio(1);
#pragma unroll
      for (int mm = 0; mm < 2; ++mm)
#pragma unroll
        for (int ni = 0; ni < 4; ++ni)
#pragma unroll
          for (int ks = 0; ks < 2; ++ks)
            acc[p * 2 + mm][ni] = __builtin_amdgcn_mfma_f32_16x16x32_bf16(
                afr[p & 1][mm][ks], bfr[ni][ks], acc[p * 2 + mm][ni], 0, 0, 0);
      __builtin_amdgcn_s_setprio(0);
      __builtin_amdgcn_sched_barrier(0);
      __builtin_amdgcn_s_barrier();
    }

    // ---- phase 3 + tile boundary ----
    asm volatile("s_waitcnt lgkmcnt(0)" ::: "memory");  // my reads of buf done
    __builtin_amdgcn_s_barrier();                       // everyone done w/ buf[t&1]
    if (t + 2 < NT) stage(t & 1, t + 2);                // restage dead buffer
    __builtin_amdgcn_sched_barrier(0);
    __builtin_amdgcn_s_setprio(1);
#pragma unroll
    for (int mm = 0; mm < 2; ++mm)
#pragma unroll
      for (int ni = 0; ni < 4; ++ni)
#pragma unroll
        for (int ks = 0; ks < 2; ++ks)
          acc[6 + mm][ni] = __builtin_amdgcn_mfma_f32_16x16x32_bf16(
              afr[1][mm][ks], bfr[ni][ks], acc[6 + mm][ni], 0, 0, 0);
    __builtin_amdgcn_s_setprio(0);
    __builtin_amdgcn_sched_barrier(0);
    if (t + 2 < NT)
      asm volatile("s_waitcnt vmcnt(8)" ::: "memory");  // tile t+1 landed (mine)
    else
      asm volatile("s_waitcnt vmcnt(0)" ::: "memory");  // tail drain
    __builtin_amdgcn_s_barrier();                       // buf[(t+1)&1] ready (all)
    if (t + 1 < NT) {
      // issue next tile's (p=0) A-frags + B-frags (12 ds_reads)
#pragma unroll
      for (int mm = 0; mm < 2; ++mm)
#pragma unroll
        for (int ks = 0; ks < 2; ++ks)
          afr[0][mm][ks] = *reinterpret_cast<const bf16x8*>(
              nA + aoffb + mm * 1024 + (((ks * 4 + g) ^ sx) * 8));
#pragma unroll
      for (int ni = 0; ni < 4; ++ni)
#pragma unroll
        for (int ks = 0; ks < 2; ++ks)
          bfr[ni][ks] = *reinterpret_cast<const bf16x8*>(
              nB + boffb + ni * 1024 + (((ks * 4 + g) ^ sx) * 8));
      __builtin_amdgcn_sched_barrier(0);
    }
  }
}

// ------------- fused W-convert + LayerNorm (block-granular split) ---------
__global__ __launch_bounds__(256) void k_pre(const float* __restrict__ x,
                                             const float* __restrict__ gamma,
                                             const float* __restrict__ beta,
                                             const float* __restrict__ wq,
                                             const float* __restrict__ wk,
                                             const float* __restrict__ wv,
                                             bf16* __restrict__ xn,
                                             bf16* __restrict__ wall) {
  const int bid = (int)blockIdx.x;
  const int tid = (int)threadIdx.x;
  if (bid >= BATCH * SEQ) {
    int i4 = (bid - BATCH * SEQ) * 256 + tid;
    int m = i4 >> 18;
    int loc = i4 & 262143;
    const float* src = (m == 0) ? wq : (m == 1) ? wk : wv;
    float4 v = reinterpret_cast<const float4*>(src)[loc];
    bf16x4 o;
    o[0] = (bf16)v.x; o[1] = (bf16)v.y; o[2] = (bf16)v.z; o[3] = (bf16)v.w;
    reinterpret_cast<bf16x4*>(wall)[i4] = o;
    return;
  }
  const int row = bid;
  const float4 v = reinterpret_cast<const float4*>(x + (size_t)row * EMBED)[tid];
  float s = v.x + v.y + v.z + v.w;
  float q = v.x * v.x + v.y * v.y + v.z * v.z + v.w * v.w;
#pragma unroll
  for (int off = 1; off < 64; off <<= 1) {
    s += __shfl_xor(s, off);
    q += __shfl_xor(q, off);
  }
  __shared__ float ls[4], lq[4];
  int w = tid >> 6;
  if ((tid & 63) == 0) { ls[w] = s; lq[w] = q; }
  __syncthreads();
  s = ls[0] + ls[1] + ls[2] + ls[3];
  q = lq[0] + lq[1] + lq[2] + lq[3];
  float mean = s * (1.0f / EMBED);
  float var = q * (1.0f / EMBED) - mean * mean;
  float rstd = rsqrtf(var + 1e-5f);
  float4 gm = reinterpret_cast<const float4*>(gamma)[tid];
  float4 b = reinterpret_cast<const float4*>(beta)[tid];
  bf16x4 o;
  o[0] = (bf16)((v.x - mean) * rstd * gm.x + b.x);
  o[1] = (bf16)((v.y - mean) * rstd * gm.y + b.y);
  o[2] = (bf16)((v.z - mean) * rstd * gm.z + b.z);
  o[3] = (bf16)((v.w - mean) * rstd * gm.w + b.w);
  reinterpret_cast<bf16x4*>(xn + (size_t)row * EMBED)[tid] = o;
}

// ---------------- QKV projection, XCD-chunked 1D grid (768) ----------------
__global__ __launch_bounds__(512) void k_qkv256(const bf16* __restrict__ xn,
                                                const bf16* __restrict__ wall,
                                                const float* __restrict__ bq,
                                                const float* __restrict__ bk,
                                                const float* __restrict__ bv,
                                                bf16* __restrict__ qbuf,
                                                bf16* __restrict__ kbuf,
                                                bf16* __restrict__ vt) {
  extern __shared__ bf16 smem[];
  const int h = (int)blockIdx.x;
  const int xcd = h & 7, pos = h >> 3;
  const int z = pos >> 5;
  const int mtile = xcd * 8 + ((pos >> 2) & 7);
  const int ntile = pos & 3;
  const int tid = (int)threadIdx.x, lane = tid & 63, wid = tid >> 6;
  const int wm = wid >> 2, wn = wid & 3;
  const int cc = lane & 15, g = lane >> 4;
  const bf16* Ab = xn + (size_t)(mtile * 256) * EMBED;
  const bf16* Bb = wall + (size_t)z * EMBED * EMBED + (size_t)(ntile * 256) * EMBED;
  f32x4 acc[8][4];
#pragma unroll
  for (int i = 0; i < 8; ++i)
#pragma unroll
    for (int j = 0; j < 4; ++j) acc[i][j] = (f32x4){0.f, 0.f, 0.f, 0.f};
  gemm_core<EMBED, EMBED, EMBED>(Ab, Bb, smem, acc);

  const int c0 = ntile * 256 + wn * 64;
  const int r0 = mtile * 256 + wm * 128;
  if (z < 2) {
    bf16* o = z ? kbuf : qbuf;
    const float* bias = z ? bk : bq;
#pragma unroll
    for (int mi = 0; mi < 8; ++mi)
#pragma unroll
      for (int ni = 0; ni < 4; ++ni) {
        int col = c0 + ni * 16 + cc;
        float bb = bias[col];
#pragma unroll
        for (int j = 0; j < 4; ++j)
          o[(size_t)(r0 + mi * 16 + g * 4 + j) * EMBED + col] = (bf16)(acc[mi][ni][j] + bb);
      }
  } else {
#pragma unroll
    for (int mi = 0; mi < 8; ++mi) {
      int srow = r0 + mi * 16 + g * 4;
      int b = srow >> 11, sl = srow & (SEQ - 1);
#pragma unroll
      for (int ni = 0; ni < 4; ++ni) {
        int col = c0 + ni * 16 + cc;
        float bb = bv[col];
        bf16x4 pk;
#pragma unroll
        for (int j = 0; j < 4; ++j) pk[j] = (bf16)(acc[mi][ni][j] + bb);
        *reinterpret_cast<bf16x4*>(vt + (size_t)b * EMBED * SEQ + (size_t)col * SEQ + sl) = pk;
      }
    }
  }
}

// ------- Scores: XCD-chunked 1D grid (512); XCD k <- batch k ----------
__global__ __launch_bounds__(512) void k_scores256(const bf16* __restrict__ qm,
                                                   const bf16* __restrict__ km,
                                                   bf16* __restrict__ wbf,
                                                   float* __restrict__ partial) {
  extern __shared__ bf16 smem[];
  const int h = (int)blockIdx.x;
  const int bb = h & 7, pos = h >> 3;
  const int mtile = pos >> 3, ntile = pos & 7;
  const int tid = (int)threadIdx.x, lane = tid & 63, wid = tid >> 6;
  const int wm = wid >> 2, wn = wid & 3;
  const int cc = lane & 15, g = lane >> 4;
  const bf16* Ab = qm + (size_t)bb * SEQ * EMBED + (size_t)(mtile * 256) * EMBED;
  const bf16* Bb = km + (size_t)bb * SEQ * EMBED + (size_t)(ntile * 256) * EMBED;
  f32x4 acc[8][4];
#pragma unroll
  for (int i = 0; i < 8; ++i)
#pragma unroll
    for (int j = 0; j < 4; ++j) acc[i][j] = (f32x4){0.f, 0.f, 0.f, 0.f};
  gemm_core<EMBED, EMBED, EMBED>(Ab, Bb, smem, acc);

  float* red = (float*)smem;  // 256 rows x 4 waveN
  const int c0 = ntile * 256 + wn * 64;
#pragma unroll
  for (int mi = 0; mi < 8; ++mi) {
#pragma unroll
    for (int j = 0; j < 4; ++j) {
      int lrow = wm * 128 + mi * 16 + g * 4 + j;
      size_t grow = (size_t)bb * SEQ + mtile * 256 + lrow;
      float s = 0.f;
#pragma unroll
      for (int ni = 0; ni < 4; ++ni) {
        float e = __expf(acc[mi][ni][j] * 0.03125f);
        wbf[grow * SEQ + c0 + ni * 16 + cc] = (bf16)e;
        s += e;
      }
      s += __shfl_xor(s, 1);
      s += __shfl_xor(s, 2);
      s += __shfl_xor(s, 4);
      s += __shfl_xor(s, 8);
      if (cc == 0) red[lrow * 4 + wn] = s;
    }
  }
  __syncthreads();
  if (tid < 256) {
    float l = red[tid * 4 + 0] + red[tid * 4 + 1] + red[tid * 4 + 2] + red[tid * 4 + 3];
    partial[((size_t)bb * SEQ + mtile * 256 + tid) * 8 + ntile] = l;
  }
}

// ---------------- rowsum -> rinv ----------------
__global__ __launch_bounds__(256) void k_rowsum(const float* __restrict__ partial,
                                                float* __restrict__ rinv) {
  int row = blockIdx.x * 256 + threadIdx.x;
  const float* p = partial + (size_t)row * 8;
  float l = 0.f;
#pragma unroll
  for (int i = 0; i < 8; ++i) l += p[i];
  rinv[row] = 1.0f / l;
}

// ------- PV: XCD-chunked 1D grid (256); XCD k <- batch k + rinv + residual --
__global__ __launch_bounds__(512) void k_pv256(const bf16* __restrict__ wbf,
                                               const bf16* __restrict__ vt,
                                               const float* __restrict__ rinv,
                                               const float* __restrict__ xin,
                                               float* __restrict__ outp) {
  extern __shared__ bf16 smem[];
  const int h = (int)blockIdx.x;
  const int bb = h & 7, pos = h >> 3;
  const int mtile = pos >> 2, ntile = pos & 3;
  const int tid = (int)threadIdx.x, lane = tid & 63, wid = tid >> 6;
  const int wm = wid >> 2, wn = wid & 3;
  const int cc = lane & 15, g = lane >> 4;
  const bf16* Ab = wbf + (size_t)bb * SEQ * SEQ + (size_t)(mtile * 256) * SEQ;
  const bf16* Bb = vt + (size_t)bb * EMBED * SEQ + (size_t)(ntile * 256) * SEQ;
  f32x4 acc[8][4];
#pragma unroll
  for (int i = 0; i < 8; ++i)
#pragma unroll
    for (int j = 0; j < 4; ++j) acc[i][j] = (f32x4){0.f, 0.f, 0.f, 0.f};
  gemm_core<SEQ, SEQ, SEQ>(Ab, Bb, smem, acc);

  const int c0 = ntile * 256 + wn * 64;
#pragma unroll
  for (int mi = 0; mi < 8; ++mi) {
#pragma unroll
    for (int j = 0; j < 4; ++j) {
      size_t grow = (size_t)bb * SEQ + mtile * 256 + wm * 128 + mi * 16 + g * 4 + j;
      float ri = rinv[grow];
      size_t base = grow * EMBED;
#pragma unroll
      for (int ni = 0; ni < 4; ++ni) {
        size_t off = base + c0 + ni * 16 + cc;
        outp[off] = xin[off] + acc[mi][ni][j] * ri;
      }
    }
  }
}

// -------- normalize: attn_fp32 = bf16(exp) * rinv  (192 MB pass) ---------
__global__ __launch_bounds__(256) void k_norm_bf(const bf16* __restrict__ wbf,
                                                 const float* __restrict__ rinv,
                                                 float* __restrict__ attn) {
  size_t i8 = (size_t)blockIdx.x * 256 + threadIdx.x;
  int row = (int)(i8 >> 8);  // 256 chunks per 2048-elem row
  float ri = rinv[row];
  bf16x8 v = reinterpret_cast<const bf16x8*>(wbf)[i8];
  float4 lo, hi;
  lo.x = (float)v[0] * ri; lo.y = (float)v[1] * ri;
  lo.z = (float)v[2] * ri; lo.w = (float)v[3] * ri;
  hi.x = (float)v[4] * ri; hi.y = (float)v[5] * ri;
  hi.z = (float)v[6] * ri; hi.w = (float)v[7] * ri;
  reinterpret_cast<float4*>(attn)[i8 * 2] = lo;
  reinterpret_cast<float4*>(attn)[i8 * 2 + 1] = hi;
}

extern "C" void kernel_launch(void* const* d_in, const int* in_sizes, int n_in,
                              void* d_out, int out_size, void* d_ws, size_t ws_size,
                              hipStream_t stream) {
  const float* x = (const float*)d_in[0];
  const float* Wq = (const float*)d_in[1];
  const float* bq = (const float*)d_in[2];
  const float* Wk = (const float*)d_in[3];
  const float* bk = (const float*)d_in[4];
  const float* Wv = (const float*)d_in[5];
  const float* bv = (const float*)d_in[6];
  const float* gamma = (const float*)d_in[7];
  const float* beta = (const float*)d_in[8];

  float* out = (float*)d_out;
  float* attn = out + (size_t)BATCH * SEQ * EMBED;

  bf16* qbuf = (bf16*)d_out;  // Q,K live in the output region until PV
  bf16* kbuf = qbuf + (size_t)BATCH * SEQ * EMBED;

  // ws: [0,32M) xn | [32M,38M) W bf16 | later [0,64M) wbf | [64M,96M) Vt
  //     [96M,96.5M) partial (16384x8 f32) | [96.5M,+64K) rinv
  bf16* xn = (bf16*)d_ws;
  bf16* wall = xn + (size_t)BATCH * SEQ * EMBED;
  bf16* wbf = (bf16*)d_ws;
  bf16* vt = (bf16*)d_ws + (size_t)BATCH * SEQ * SEQ;
  float* partial = (float*)((char*)d_ws + 100663296ull);
  float* rinv = (float*)((char*)d_ws + 100663296ull + 524288ull);

  hipFuncSetAttribute((const void*)k_qkv256, hipFuncAttributeMaxDynamicSharedMemorySize, 131072);
  hipFuncSetAttribute((const void*)k_scores256, hipFuncAttributeMaxDynamicSharedMemorySize, 131072);
  hipFuncSetAttribute((const void*)k_pv256, hipFuncAttributeMaxDynamicSharedMemorySize, 131072);

  k_pre<<<BATCH * SEQ + 3072, 256, 0, stream>>>(x, gamma, beta, Wq, Wk, Wv, xn, wall);
  k_qkv256<<<768, 512, 131072, stream>>>(xn, wall, bq, bk, bv, qbuf, kbuf, vt);
  k_scores256<<<512, 512, 131072, stream>>>(qbuf, kbuf, wbf, partial);
  k_rowsum<<<64, 256, 0, stream>>>(partial, rinv);
  k_pv256<<<256, 512, 131072, stream>>>(wbf, vt, rinv, x, out);
  k_norm_bf<<<16384, 256, 0, stream>>>(wbf, rinv, attn);
}